// Round 8
// baseline (728.781 us; speedup 1.0000x reference)
//
#include <hip/hip_runtime.h>
#include <cstdint>
#include <cstddef>

typedef unsigned short u16;
typedef __attribute__((ext_vector_type(8))) short bf16x8;   // 8 bf16 = 4 VGPRs
typedef __attribute__((ext_vector_type(4))) float f32x4;    // MFMA accumulator

#define DEVFN static __device__ __forceinline__

DEVFN u16 f2bf(float f) {
  unsigned u = __float_as_uint(f);
  unsigned r = (u + 0x7FFFu + ((u >> 16) & 1u)) >> 16;   // RTN-even
  return (u16)r;
}

// async global->LDS, 16B/lane. LDS dest = wave-uniform base + lane*16 (m104/m108).
DEVFN void gload16(const void* g, void* l) {
  __builtin_amdgcn_global_load_lds(
      (const __attribute__((address_space(1))) void*)g,
      (__attribute__((address_space(3))) void*)l, 16, 0, 0);
}

// counted waits + raw barrier (compiler memory fences keep LDS ops ordered)
#define WAITVM(n) asm volatile("s_waitcnt vmcnt(" #n ")" ::: "memory")
#define BARRIER() do { asm volatile("" ::: "memory"); \
                       __builtin_amdgcn_s_barrier();   \
                       asm volatile("" ::: "memory"); } while (0)
// Phase close: retire this phase's ds_reads (lgkmcnt 0), pin the schedule, barrier.
// After this, the LDS region this phase consumed is DEAD -> safe to restage (R10 core).
#define PHASE_END() do { asm volatile("s_waitcnt lgkmcnt(0)" ::: "memory"); \
                         __builtin_amdgcn_sched_barrier(0);                 \
                         __builtin_amdgcn_s_barrier();                      \
                         asm volatile("" ::: "memory"); } while (0)
// Wave-internal LDS write->read fence (R9, rule #18): cross-lane P round-trip is
// invisible to LLVM's per-lane alias analysis.
#define FENCE_LDS() do { asm volatile("s_waitcnt lgkmcnt(0)" ::: "memory"); \
                         __builtin_amdgcn_sched_barrier(0); } while (0)

// ---------------- merged prep: converts + wqkv row-permute + cos/sin table ----------------
// wqkv q/k rows interleaved per head: d<64 -> 2d, d>=64 -> 2(d-64)+1  (QK^T invariant).
// cs[l*64+m] = (cos(l,m), sin(l,m))
__global__ void prep(const float* __restrict__ x, const float* __restrict__ wqkv,
                     const float* __restrict__ wout, const float* __restrict__ cosp,
                     const float* __restrict__ sinp, u16* __restrict__ xb,
                     u16* __restrict__ wqkvb, u16* __restrict__ woutb,
                     float2* __restrict__ cs) {
  constexpr int X4 = 4194304;      // x elems/4
  constexpr int W4 = 3145728;      // wqkv elems/4
  constexpr int O4 = 1048576;      // wout elems/4
  int i = blockIdx.x * blockDim.x + threadIdx.x;
  if (i < X4) {
    float4 v = ((const float4*)x)[i];
    unsigned long long w = (unsigned long long)f2bf(v.x)
        | ((unsigned long long)f2bf(v.y) << 16)
        | ((unsigned long long)f2bf(v.z) << 32)
        | ((unsigned long long)f2bf(v.w) << 48);
    *(unsigned long long*)(xb + (size_t)i * 4) = w;
  } else if (i < X4 + W4) {
    int j = i - X4;
    int base = j * 4;
    int e = base >> 11, col = base & 2047;
    int e2;
    if (e < 4096) {
      int part = e >> 11, loc = e & 2047;
      int h = loc >> 7, d = loc & 127;
      int d2 = (d < 64) ? 2 * d : 2 * (d - 64) + 1;
      e2 = part * 2048 + h * 128 + d2;
    } else {
      e2 = e;                      // v rows unpermuted
    }
    float4 v = *(const float4*)&wqkv[(size_t)base];
    unsigned long long w = (unsigned long long)f2bf(v.x)
        | ((unsigned long long)f2bf(v.y) << 16)
        | ((unsigned long long)f2bf(v.z) << 32)
        | ((unsigned long long)f2bf(v.w) << 48);
    *(unsigned long long*)(wqkvb + (size_t)e2 * 2048 + col) = w;
  } else if (i < X4 + W4 + O4) {
    int j = i - X4 - W4;
    float4 v = ((const float4*)wout)[j];
    unsigned long long w = (unsigned long long)f2bf(v.x)
        | ((unsigned long long)f2bf(v.y) << 16)
        | ((unsigned long long)f2bf(v.z) << 32)
        | ((unsigned long long)f2bf(v.w) << 48);
    *(unsigned long long*)(woutb + (size_t)j * 4) = w;
  } else {
    int k = i - X4 - W4 - O4;      // < 32768
    int ld4 = k * 4;
#pragma unroll
    for (int u = 0; u < 4; u++) {
      int ld = ld4 + u;
      int l = ld >> 6, d = ld & 63;
      cs[ld] = make_float2(cosp[(size_t)l * 128 + d], sinp[(size_t)l * 128 + d]);
    }
  }
}

// ========== 256x256 GEMM core, R10: single-buffer freed-region schedule ==========
// BM=BN=256, BK=64, 512 thr = 8 waves (2M x 4N), wave output 128x64 = acc[8][4].
// LDS: A[256*64] + B[256*64] bf16 = 64 KB, SINGLE buffer. Key invariant: phase p
// consumes region(p) entirely into registers (B+Aq0 in ph1; Aq1..3 in ph2..4) and
// PHASE_END retires the reads -> region(p) is dead after ph p -> restage it for
// tile t+1 immediately. Every load thus has 3-4 phases (~1200-1600 cy) to land,
// covering L3/HBM latency (R4 port's A0 had only 2 phases -> ph1 vmcnt stall).
// Ledger (8 outstanding at every wait): ph1 vmcnt(3) [drain B+A0(t), 5 ops],
// ph2..4 vmcnt(7) [drain Aq(t), 1 op]. Never 0 in main loop; last tile peeled
// with 3/2/1/0. Issue order per tile: B0,B1,A0 | A1 | A2 | A3 (oldest-first).
enum { M_F32OUT = 0, M_ROPE = 1, M_VT = 2 };

DEVFN bf16x8 rdfrag(const u16* buf, int row, int chunk) {
  return *(const bf16x8*)&buf[row * 64 + (((chunk ^ (row & 7)) & 7) << 3)];
}

template <int MODE, int Q>
DEVFN void phase_mfma(const u16* Ac, const u16* Bc, int wm, int wn, int quad, int l16,
                      bf16x8 (&bfr)[4][2], f32x4 (&acc)[8][4]) {
  if (Q == 0) {
#pragma unroll
    for (int j = 0; j < 4; j++)
#pragma unroll
      for (int kk = 0; kk < 2; kk++)
        bfr[j][kk] = rdfrag(Bc, wn * 64 + j * 16 + l16, kk * 4 + quad);
  }
  bf16x8 af[2][2];
#pragma unroll
  for (int i2 = 0; i2 < 2; i2++)
#pragma unroll
    for (int kk = 0; kk < 2; kk++)
      af[i2][kk] = rdfrag(Ac, wm * 128 + (Q * 2 + i2) * 16 + l16, kk * 4 + quad);
  __builtin_amdgcn_s_setprio(1);
#pragma unroll
  for (int kk = 0; kk < 2; kk++)
#pragma unroll
    for (int i2 = 0; i2 < 2; i2++)
#pragma unroll
      for (int j = 0; j < 4; j++) {
        if (MODE == M_VT)
          acc[Q * 2 + i2][j] = __builtin_amdgcn_mfma_f32_16x16x32_bf16(
              bfr[j][kk], af[i2][kk], acc[Q * 2 + i2][j], 0, 0, 0);
        else
          acc[Q * 2 + i2][j] = __builtin_amdgcn_mfma_f32_16x16x32_bf16(
              af[i2][kk], bfr[j][kk], acc[Q * 2 + i2][j], 0, 0, 0);
      }
  __builtin_amdgcn_s_setprio(0);
}

template <int MODE>
DEVFN void gemm256_core(const u16* __restrict__ A, const u16* __restrict__ Bt,
                        void* __restrict__ Cv, const float2* __restrict__ cs,
                        int N, int m0, int n0, u16* As, u16* Bs) {
  int tid = threadIdx.x;
  int wv = tid >> 6, lane = tid & 63, quad = lane >> 4, l16 = lane & 15;
  int wm = wv >> 2, wn = wv & 3;

  // per-thread pre-swizzled global source pointers (advance by k elems per tile)
  const u16* pB[2][2];
  const u16* pA[4];
#pragma unroll
  for (int h = 0; h < 2; h++)
#pragma unroll
    for (int o = 0; o < 2; o++) {
      int r = h * 128 + o * 64 + wv * 8 + (lane >> 3);
      int ck = (lane & 7) ^ (r & 7);
      pB[h][o] = Bt + (size_t)(n0 + r) * 2048 + ck * 8;
    }
#pragma unroll
  for (int q = 0; q < 4; q++) {
    int rb = (wv < 4) ? (q * 32 + wv * 8) : (128 + q * 32 + (wv - 4) * 8);
    int r = rb + (lane >> 3);
    int ck = (lane & 7) ^ (r & 7);
    pA[q] = A + (size_t)(m0 + r) * 2048 + ck * 8;
  }

#define STAGE_B(h, kk) do {                                         \
    int rb0_ = (h) * 128 + wv * 8;                                  \
    gload16(pB[h][0] + (kk), &Bs[rb0_ * 64]);                       \
    gload16(pB[h][1] + (kk), &Bs[(rb0_ + 64) * 64]); } while (0)
#define STAGE_A(q, kk) do {                                         \
    int rb_ = ((wv < 4) ? ((q) * 32 + wv * 8)                       \
                        : (128 + (q) * 32 + (wv - 4) * 8));         \
    gload16(pA[q] + (kk), &As[rb_ * 64]); } while (0)

  f32x4 acc[8][4] = {};
  bf16x8 bfr[4][2];

  // prologue: stage tile 0 (issue order = ledger order: B0,B1,A0 | A1 | A2 | A3)
  STAGE_B(0, 0);
  STAGE_B(1, 0);
  STAGE_A(0, 0);
  STAGE_A(1, 0);
  STAGE_A(2, 0);
  STAGE_A(3, 0);

  for (int t = 0; t < 31; t++) {
    int kn = (t + 1) * 64;
    WAITVM(3); BARRIER();                      // B+A0(t) landed (5 oldest)
    phase_mfma<MODE, 0>(As, Bs, wm, wn, quad, l16, bfr, acc);
    PHASE_END();                               // B + Aq0 regions now dead
    STAGE_B(0, kn); STAGE_B(1, kn); STAGE_A(0, kn);
    WAITVM(7); BARRIER();                      // A1(t) landed
    phase_mfma<MODE, 1>(As, Bs, wm, wn, quad, l16, bfr, acc);
    PHASE_END();
    STAGE_A(1, kn);
    WAITVM(7); BARRIER();                      // A2(t) landed
    phase_mfma<MODE, 2>(As, Bs, wm, wn, quad, l16, bfr, acc);
    PHASE_END();
    STAGE_A(2, kn);
    WAITVM(7); BARRIER();                      // A3(t) landed
    phase_mfma<MODE, 3>(As, Bs, wm, wn, quad, l16, bfr, acc);
    PHASE_END();
    STAGE_A(3, kn);
  }
  {  // peeled last tile: no staging, drain 3/2/1/0
    WAITVM(3); BARRIER();
    phase_mfma<MODE, 0>(As, Bs, wm, wn, quad, l16, bfr, acc);
    PHASE_END();
    WAITVM(2); BARRIER();
    phase_mfma<MODE, 1>(As, Bs, wm, wn, quad, l16, bfr, acc);
    PHASE_END();
    WAITVM(1); BARRIER();
    phase_mfma<MODE, 2>(As, Bs, wm, wn, quad, l16, bfr, acc);
    PHASE_END();
    WAITVM(0); BARRIER();
    phase_mfma<MODE, 3>(As, Bs, wm, wn, quad, l16, bfr, acc);
  }
#undef STAGE_B
#undef STAGE_A

  // ---- epilogue: C/D layout col = lane&15, row = quad*4 + reg (m89/m91 verified) ----
  if (MODE == M_F32OUT) {
    float* C = (float*)Cv;
#pragma unroll
    for (int i = 0; i < 8; i++)
#pragma unroll
      for (int r = 0; r < 4; r++) {
        size_t row = (size_t)(m0 + wm * 128 + i * 16 + quad * 4 + r);
#pragma unroll
        for (int j = 0; j < 4; j++)
          C[row * N + (n0 + wn * 64 + j * 16 + l16)] = acc[i][j][r];
      }
  } else if (MODE == M_ROPE) {
    constexpr float QSCALE = 1.4426950408889634f * 0.08838834764831845f;
    const float scale = (n0 >> 11) ? 1.0f : QSCALE;   // q gets log2e/sqrt(128)
    u16* C = (u16*)Cv;
#pragma unroll
    for (int i = 0; i < 8; i++)
#pragma unroll
      for (int r = 0; r < 4; r++) {
        int row = m0 + wm * 128 + i * 16 + quad * 4 + r;
        int l = row & 2047;
#pragma unroll
        for (int j = 0; j < 4; j++) {
          int col = n0 + wn * 64 + j * 16 + l16;
          int dm = (col & 127) >> 1;
          float2 csv = cs[l * 64 + dm];
          float v = acc[i][j][r];
          float pv = __shfl_xor(v, 1);                 // partner lane (col^1)
          float sg = (l16 & 1) ? csv.y : -csv.y;       // even: -sin, odd: +sin
          C[(size_t)row * 4096 + col] = f2bf((v * csv.x + pv * sg) * scale);
        }
      }
  } else {
    // VT: swapped operands -> acc holds C^T; row = v-channel, col = token. vt[bh][d][l].
    u16* vt = (u16*)Cv;
#pragma unroll
    for (int j = 0; j < 4; j++)
#pragma unroll
      for (int r = 0; r < 4; r++) {
        int vch = n0 + wn * 64 + j * 16 + quad * 4 + r;   // 0..2047
        int h = vch >> 7, d = vch & 127;
#pragma unroll
        for (int i = 0; i < 8; i++) {
          int token = m0 + wm * 128 + i * 16 + l16;
          int b = token >> 11, lloc = token & 2047;
          vt[((size_t)(b * 16 + h)) * 262144 + (size_t)d * 2048 + lloc] =
              f2bf(acc[i][j][r]);
        }
      }
  }
}

// Merged QKV GEMM: bx<16 -> RoPE epilogue into qkv (stride 4096); bx>=16 -> V^T.
// XCD y-striping: each XCD owns a 4-row stripe of M-tiles (A rows L2-resident).
__global__ __launch_bounds__(512, 2) void gemm_qkv(const u16* __restrict__ xb,
                                                   const u16* __restrict__ wqkvb,
                                                   u16* __restrict__ qkvo,
                                                   u16* __restrict__ vto,
                                                   const float2* __restrict__ cs) {
  __shared__ u16 As[16384];
  __shared__ u16 Bs[16384];
  int id = blockIdx.x;
  int xcd = id & 7, sub = id >> 3;      // sub 0..95
  int bx = sub % 24, by = xcd * 4 + sub / 24;
  if (bx < 16)
    gemm256_core<M_ROPE>(xb, wqkvb, qkvo, cs, 0, by * 256, bx * 256, As, Bs);
  else
    gemm256_core<M_VT>(xb, wqkvb + (size_t)4096 * 2048, vto, nullptr, 0,
                       by * 256, (bx - 16) * 256, As, Bs);
}

__global__ __launch_bounds__(512, 2) void gemm_out_k(const u16* __restrict__ A,
                                                     const u16* __restrict__ Bt,
                                                     float* __restrict__ C) {
  __shared__ u16 As[16384];
  __shared__ u16 Bs[16384];
  int id = blockIdx.x;
  int xcd = id & 7, sub = id >> 3;      // sub 0..31
  int bx = sub % 8, by = xcd * 4 + sub / 8;
  gemm256_core<M_F32OUT>(A, Bt, C, nullptr, 2048, by * 256, bx * 256, As, Bs);
}

// ---------------- fused flash attention (fixed-base softmax, no online max) ----------------
// R9 (verified): 256 thr / 4 waves / 32 q-rows per wave (each K/V fragment read feeds
// TWO row-tiles), KVBLK=32, double-buffered K (2x8KB) + V (2x8KB) + padded P
// (128 x 40 = 10KB) = 43KB LDS -> 3 blocks/CU, 12 waves/CU. FENCE_LDS between the
// P-write loop and pf reads (R8 failure: compiler hoisted the cross-lane ds_read).
DEVFN int swz(int row, int chunk)   { return row * 128 + ((chunk ^ (row & 15)) << 3); } // 256B rows
DEVFN int swz32(int row, int chunk) { return row * 32  + (((chunk ^ (row & 3)) & 3) << 3); } // 64B rows

__global__ __launch_bounds__(256, 3) void attn_fused(const u16* __restrict__ qkv,
                                                     const u16* __restrict__ vt,
                                                     u16* __restrict__ out) {
  // S layout (u16 units): [0,4096)=Kb0 [4096,8192)=Kb1
  //                       [8192,12288)=Vb0 [12288,16384)=Vb1
  //                       [16384,21504)=P (128 rows x 40 elems, 80B stride: bank-spread)
  __shared__ u16 S[21504];                     // 43008 B
  u16* const Pb = S + 16384;
  int tid = threadIdx.x;
  int wv = tid >> 6, lane = tid & 63, quad = lane >> 4, l16 = lane & 15;
  int id = blockIdx.x;
  int xcd = id & 7, sub = id >> 3;             // sub 0..127
  int bh = ((sub >> 4) << 3) | xcd;            // 8 bh per XCD, all 16 qtiles local
  int qt = sub & 15;
  int b = bh >> 4, hh = bh & 15;
  const u16* qptr = qkv + (size_t)b * 2048 * 4096 + hh * 128;
  const u16* kptr = qptr + 2048;
  const u16* vptr = vt + (size_t)bh * 262144;
  int q0 = qt * 128;

  // ---- Q staging: 128 rows x 256B through S[0..16384), then pull to regs ----
#pragma unroll
  for (int j = 0; j < 8; j++) {
    int rb = wv * 4 + j * 16;
    int r = rb + (lane >> 4);
    int ck = (lane & 15) ^ (r & 15);
    gload16(&qptr[(size_t)(q0 + r) * 4096 + ck * 8], &S[rb * 128]);
  }
  __syncthreads();
  bf16x8 qf[2][4];
#pragma unroll
  for (int hf = 0; hf < 2; hf++)
#pragma unroll
    for (int ks = 0; ks < 4; ks++)
      qf[hf][ks] = *(const bf16x8*)&S[swz(wv * 32 + hf * 16 + l16, ks * 4 + quad)];
  __syncthreads();                             // qf reads done before kt=0 staging

  f32x4 o[2][8] = {};
  float l[2][4] = {{0.f, 0.f, 0.f, 0.f}, {0.f, 0.f, 0.f, 0.f}};

  // prologue: stage kt=0 into Kb0/Vb0 (K: 32 rows x 256B; V^T: 128 rows x 64B)
#pragma unroll
  for (int j = 0; j < 2; j++) {
    int rbk = wv * 4 + j * 16;
    int rk = rbk + (lane >> 4);
    int ckk = (lane & 15) ^ (rk & 15);
    gload16(&kptr[(size_t)rk * 4096 + ckk * 8], &S[rbk * 128]);
    int rbv = wv * 16 + j * 64;
    int rv = rbv + (lane >> 2);
    int ckv = (lane & 3) ^ (rv & 3);
    gload16(&vptr[(size_t)rv * 2048 + ckv * 8], &S[8192 + rbv * 32]);
  }

  for (int kt = 0; kt < 64; kt++) {
    int cur = kt & 1;
    const u16* Kc = S + cur * 4096;
    const u16* Vc = S + 8192 + cur * 4096;
    __syncthreads();   // auto vmcnt(0): drains cur-tile loads (1 iter old) + prior reads
    if (kt < 63) {     // prefetch kt+1 into the other buffer set
      int kk0 = (kt + 1) * 32;
      u16* kb = S + (cur ^ 1) * 4096;
      u16* vb = S + 8192 + (cur ^ 1) * 4096;
#pragma unroll
      for (int j = 0; j < 2; j++) {
        int rbk = wv * 4 + j * 16;
        int rk = rbk + (lane >> 4);
        int ckk = (lane & 15) ^ (rk & 15);
        gload16(&kptr[(size_t)(kk0 + rk) * 4096 + ckk * 8], &kb[rbk * 128]);
        int rbv = wv * 16 + j * 64;
        int rv = rbv + (lane >> 2);
        int ckv = (lane & 3) ^ (rv & 3);
        gload16(&vptr[(size_t)rv * 2048 + kk0 + ckv * 8], &vb[rbv * 32]);
      }
    }
    // S = Q K^T (scores in log2 domain via QSCALE folded into q).
    // One K-frag read feeds BOTH row-halves (the traffic halving).
    f32x4 s[2][2] = {};
#pragma unroll
    for (int ks = 0; ks < 4; ks++) {
#pragma unroll
      for (int nt = 0; nt < 2; nt++) {
        bf16x8 bfr = *(const bf16x8*)&Kc[swz(nt * 16 + l16, ks * 4 + quad)];
        s[0][nt] = __builtin_amdgcn_mfma_f32_16x16x32_bf16(qf[0][ks], bfr, s[0][nt], 0, 0, 0);
        s[1][nt] = __builtin_amdgcn_mfma_f32_16x16x32_bf16(qf[1][ks], bfr, s[1][nt], 0, 0, 0);
      }
    }
    // fixed-base softmax: p = exp2(s); lane-local row-sum; P -> padded private buffer
#pragma unroll
    for (int hf = 0; hf < 2; hf++)
#pragma unroll
      for (int nt = 0; nt < 2; nt++)
#pragma unroll
        for (int r = 0; r < 4; r++) {
          float p = exp2f(s[hf][nt][r]);
          l[hf][r] += p;
          int row = wv * 32 + hf * 16 + quad * 4 + r;
          int col = nt * 16 + l16;
          Pb[row * 40 + col] = f2bf(p);
        }
    // cross-lane P round-trip: force all P ds_writes to retire before pf ds_reads
    FENCE_LDS();
    // O += P V  (Vc holds V^T: rows = d, cols = 32 keys; K=32 -> one MFMA per tile).
    // One V-frag read feeds BOTH row-halves.
    {
      bf16x8 pf0 = *(const bf16x8*)&Pb[(wv * 32 + l16) * 40 + quad * 8];
      bf16x8 pf1 = *(const bf16x8*)&Pb[(wv * 32 + 16 + l16) * 40 + quad * 8];
#pragma unroll
      for (int nt = 0; nt < 8; nt++) {
        bf16x8 vf = *(const bf16x8*)&Vc[swz32(nt * 16 + l16, quad)];
        o[0][nt] = __builtin_amdgcn_mfma_f32_16x16x32_bf16(pf0, vf, o[0][nt], 0, 0, 0);
        o[1][nt] = __builtin_amdgcn_mfma_f32_16x16x32_bf16(pf1, vf, o[1][nt], 0, 0, 0);
      }
    }
  }
  // epilogue: reduce l across the 16 col-lanes once, divide, store bf16
#pragma unroll
  for (int hf = 0; hf < 2; hf++)
#pragma unroll
    for (int r = 0; r < 4; r++)
#pragma unroll
      for (int off = 1; off < 16; off <<= 1) l[hf][r] += __shfl_xor(l[hf][r], off, 16);
  u16* obase = out + ((size_t)b * 2048 + q0) * 2048 + hh * 128;
#pragma unroll
  for (int hf = 0; hf < 2; hf++)
#pragma unroll
    for (int r = 0; r < 4; r++) {
      float inv = 1.0f / l[hf][r];
      int row = wv * 32 + hf * 16 + quad * 4 + r;
#pragma unroll
      for (int nt = 0; nt < 8; nt++)
        obase[(size_t)row * 2048 + nt * 16 + l16] = f2bf(o[hf][nt][r] * inv);
    }
}

// ---------------- launch ----------------
extern "C" void kernel_launch(void* const* d_in, const int* in_sizes, int n_in,
                              void* d_out, int out_size, void* d_ws, size_t ws_size,
                              hipStream_t stream) {
  const float* x    = (const float*)d_in[0];   // [4,2048,2048]
  const float* cosp = (const float*)d_in[1];   // [2048,128]
  const float* sinp = (const float*)d_in[2];   // [2048,128]
  const float* wqkv = (const float*)d_in[3];   // [6144,2048]
  const float* wout = (const float*)d_in[4];   // [2048,2048]
  float* outp = (float*)d_out;                 // [4,2048,2048] fp32

  u16* ws    = (u16*)d_ws;
  u16* xb    = ws;                     // 16,777,216 elems (dead after gemm_qkv; reused)
  u16* wqkvb = xb + 16777216;          // 12,582,912 (row-permuted q/k)
  u16* woutb = wqkvb + 12582912;       //  4,194,304
  u16* qkv   = woutb + 4194304;        // 33,554,432 (q,k only; row stride 4096)
  u16* vt    = qkv + 33554432;         // 16,777,216
  float2* cs = (float2*)(vt + 16777216); // 131,072 float2 = 1 MB
  u16* attn  = xb;                     // alias: xb dead after gemm_qkv

  prep<<<32896, 256, 0, stream>>>(x, wqkv, wout, cosp, sinp, xb, wqkvb, woutb, cs);
  gemm_qkv<<<768, 512, 0, stream>>>(xb, wqkvb, qkv, vt, cs);
  attn_fused<<<1024, 256, 0, stream>>>(qkv, vt, attn);
  gemm_out_k<<<256, 512, 0, stream>>>(attn, woutb, outp);
}

// Round 9
// 588.271 us; speedup vs baseline: 1.2389x; 1.2389x over previous
//
#include <hip/hip_runtime.h>
#include <cstdint>
#include <cstddef>

typedef unsigned short u16;
typedef __attribute__((ext_vector_type(8))) short bf16x8;   // 8 bf16 = 4 VGPRs
typedef __attribute__((ext_vector_type(4))) float f32x4;    // MFMA accumulator

#define DEVFN static __device__ __forceinline__

DEVFN u16 f2bf(float f) {
  unsigned u = __float_as_uint(f);
  unsigned r = (u + 0x7FFFu + ((u >> 16) & 1u)) >> 16;   // RTN-even
  return (u16)r;
}

// async global->LDS, 16B/lane. LDS dest = wave-uniform base + lane*16 (m104/m108).
DEVFN void gload16(const void* g, void* l) {
  __builtin_amdgcn_global_load_lds(
      (const __attribute__((address_space(1))) void*)g,
      (__attribute__((address_space(3))) void*)l, 16, 0, 0);
}

// counted waits + raw barrier (compiler memory fences keep LDS ops ordered)
#define WAITVM(n) asm volatile("s_waitcnt vmcnt(" #n ")" ::: "memory")
#define BARRIER() do { asm volatile("" ::: "memory"); \
                       __builtin_amdgcn_s_barrier();   \
                       asm volatile("" ::: "memory"); } while (0)
// Wave-internal LDS write->read fence (R9, rule #18): cross-lane P round-trip is
// invisible to LLVM's per-lane alias analysis.
#define FENCE_LDS() do { asm volatile("s_waitcnt lgkmcnt(0)" ::: "memory"); \
                         __builtin_amdgcn_sched_barrier(0); } while (0)

// ---------------- merged prep: converts + wqkv row-permute + cos/sin table ----------------
// wqkv q/k rows interleaved per head: d<64 -> 2d, d>=64 -> 2(d-64)+1  (QK^T invariant).
// cs[l*64+m] = (cos(l,m), sin(l,m))
__global__ void prep(const float* __restrict__ x, const float* __restrict__ wqkv,
                     const float* __restrict__ wout, const float* __restrict__ cosp,
                     const float* __restrict__ sinp, u16* __restrict__ xb,
                     u16* __restrict__ wqkvb, u16* __restrict__ woutb,
                     float2* __restrict__ cs) {
  constexpr int X4 = 4194304;      // x elems/4
  constexpr int W4 = 3145728;      // wqkv elems/4
  constexpr int O4 = 1048576;      // wout elems/4
  int i = blockIdx.x * blockDim.x + threadIdx.x;
  if (i < X4) {
    float4 v = ((const float4*)x)[i];
    unsigned long long w = (unsigned long long)f2bf(v.x)
        | ((unsigned long long)f2bf(v.y) << 16)
        | ((unsigned long long)f2bf(v.z) << 32)
        | ((unsigned long long)f2bf(v.w) << 48);
    *(unsigned long long*)(xb + (size_t)i * 4) = w;
  } else if (i < X4 + W4) {
    int j = i - X4;
    int base = j * 4;
    int e = base >> 11, col = base & 2047;
    int e2;
    if (e < 4096) {
      int part = e >> 11, loc = e & 2047;
      int h = loc >> 7, d = loc & 127;
      int d2 = (d < 64) ? 2 * d : 2 * (d - 64) + 1;
      e2 = part * 2048 + h * 128 + d2;
    } else {
      e2 = e;                      // v rows unpermuted
    }
    float4 v = *(const float4*)&wqkv[(size_t)base];
    unsigned long long w = (unsigned long long)f2bf(v.x)
        | ((unsigned long long)f2bf(v.y) << 16)
        | ((unsigned long long)f2bf(v.z) << 32)
        | ((unsigned long long)f2bf(v.w) << 48);
    *(unsigned long long*)(wqkvb + (size_t)e2 * 2048 + col) = w;
  } else if (i < X4 + W4 + O4) {
    int j = i - X4 - W4;
    float4 v = ((const float4*)wout)[j];
    unsigned long long w = (unsigned long long)f2bf(v.x)
        | ((unsigned long long)f2bf(v.y) << 16)
        | ((unsigned long long)f2bf(v.z) << 32)
        | ((unsigned long long)f2bf(v.w) << 48);
    *(unsigned long long*)(woutb + (size_t)j * 4) = w;
  } else {
    int k = i - X4 - W4 - O4;      // < 32768
    int ld4 = k * 4;
#pragma unroll
    for (int u = 0; u < 4; u++) {
      int ld = ld4 + u;
      int l = ld >> 6, d = ld & 63;
      cs[ld] = make_float2(cosp[(size_t)l * 128 + d], sinp[(size_t)l * 128 + d]);
    }
  }
}

// ========== 256x256 GEMM core, R11: R4 dbuf layout, phases merged 4 -> 2 ==========
// BM=BN=256, BK=64, 512 thr = 8 waves (2M x 4N), wave output 128x64 = acc[8][4].
// LDS: A[2][256*64] + B[2][256*64] bf16 = 128 KB, double-buffered by K-tile parity
// (identical to the verified R4 core). R10's lesson: load latency was NOT the stall
// (3-phase leads + 8 barriers/tile = 312us); barrier lockstep was (R4: 4 bar = 244us).
// So: HALVE barriers. Per tile t: 2 phases, counted vmcnt, stage t+1 one tile ahead:
//   ph1: issue B(t+1)[4 ops]   vmcnt(6)  bar  read Ball + A-quads 0,1;  32 MFMA
//   ph2: issue A(t+1)[4 ops]   vmcnt(8)  bar  read A-quads 2,3;         32 MFMA
// Ledger (entering tile: 8 outstanding = B(t)4+A(t)4): ph1 12->6 drains exactly
// {B(t), A0(t), A1(t)}; ph2 10->8 drains {A2(t), A3(t)}. Never 0 in main loop;
// peeled last tile 2/0. WAR-safety = same argument as R4 (opposite-parity staging;
// reads retired by compiler's pre-MFMA lgkmcnt before the next barrier).
enum { M_F32OUT = 0, M_ROPE = 1, M_VT = 2 };

DEVFN bf16x8 rdfrag(const u16* buf, int row, int chunk) {
  return *(const bf16x8*)&buf[row * 64 + (((chunk ^ (row & 7)) & 7) << 3)];
}

template <int MODE, int H>   // H=0: read B frags + quads 0,1.  H=1: quads 2,3.
DEVFN void half_mfma(const u16* Ac, const u16* Bc, int wm, int wn, int quad, int l16,
                     bf16x8 (&bfr)[4][2], f32x4 (&acc)[8][4]) {
  if (H == 0) {
#pragma unroll
    for (int j = 0; j < 4; j++)
#pragma unroll
      for (int kk = 0; kk < 2; kk++)
        bfr[j][kk] = rdfrag(Bc, wn * 64 + j * 16 + l16, kk * 4 + quad);
  }
  bf16x8 af[2][2][2];        // [qi][i2][kk]
#pragma unroll
  for (int qi = 0; qi < 2; qi++)
#pragma unroll
    for (int i2 = 0; i2 < 2; i2++)
#pragma unroll
      for (int kk = 0; kk < 2; kk++)
        af[qi][i2][kk] =
            rdfrag(Ac, wm * 128 + ((H * 2 + qi) * 2 + i2) * 16 + l16, kk * 4 + quad);
  __builtin_amdgcn_s_setprio(1);
#pragma unroll
  for (int qi = 0; qi < 2; qi++)
#pragma unroll
    for (int kk = 0; kk < 2; kk++)
#pragma unroll
      for (int i2 = 0; i2 < 2; i2++)
#pragma unroll
        for (int j = 0; j < 4; j++) {
          int row = (H * 2 + qi) * 2 + i2;
          if (MODE == M_VT)
            acc[row][j] = __builtin_amdgcn_mfma_f32_16x16x32_bf16(
                bfr[j][kk], af[qi][i2][kk], acc[row][j], 0, 0, 0);
          else
            acc[row][j] = __builtin_amdgcn_mfma_f32_16x16x32_bf16(
                af[qi][i2][kk], bfr[j][kk], acc[row][j], 0, 0, 0);
        }
  __builtin_amdgcn_s_setprio(0);
}

template <int MODE>
DEVFN void gemm256_core(const u16* __restrict__ A, const u16* __restrict__ Bt,
                        void* __restrict__ Cv, const float2* __restrict__ cs,
                        int N, int m0, int n0, u16* As, u16* Bs) {
  int tid = threadIdx.x;
  int wv = tid >> 6, lane = tid & 63, quad = lane >> 4, l16 = lane & 15;
  int wm = wv >> 2, wn = wv & 3;

  // per-thread pre-swizzled global source pointers (advance by k elems per tile)
  const u16* pB[2][2];
  const u16* pA[4];
#pragma unroll
  for (int h = 0; h < 2; h++)
#pragma unroll
    for (int o = 0; o < 2; o++) {
      int r = h * 128 + o * 64 + wv * 8 + (lane >> 3);
      int ck = (lane & 7) ^ (r & 7);
      pB[h][o] = Bt + (size_t)(n0 + r) * 2048 + ck * 8;
    }
#pragma unroll
  for (int q = 0; q < 4; q++) {
    int rb = (wv < 4) ? (q * 32 + wv * 8) : (128 + q * 32 + (wv - 4) * 8);
    int r = rb + (lane >> 3);
    int ck = (lane & 7) ^ (r & 7);
    pA[q] = A + (size_t)(m0 + r) * 2048 + ck * 8;
  }

#define STAGE_B(h, buf, kk) do {                                    \
    int rb0_ = (h) * 128 + wv * 8;                                  \
    gload16(pB[h][0] + (kk), &(buf)[rb0_ * 64]);                    \
    gload16(pB[h][1] + (kk), &(buf)[(rb0_ + 64) * 64]); } while (0)
#define STAGE_A(q, buf, kk) do {                                    \
    int rb_ = ((wv < 4) ? ((q) * 32 + wv * 8)                       \
                        : (128 + (q) * 32 + (wv - 4) * 8));         \
    gload16(pA[q] + (kk), &(buf)[rb_ * 64]); } while (0)

  f32x4 acc[8][4] = {};
  bf16x8 bfr[4][2];

  // prologue: stage tile 0 into buffer 0 (issue order = ledger order)
  STAGE_B(0, Bs, 0);
  STAGE_B(1, Bs, 0);
  STAGE_A(0, As, 0);
  STAGE_A(1, As, 0);
  STAGE_A(2, As, 0);
  STAGE_A(3, As, 0);

  for (int t = 0; t < 31; t++) {
    const u16* Ac = As + (t & 1) * 16384;
    const u16* Bc = Bs + (t & 1) * 16384;
    u16* An = As + ((t + 1) & 1) * 16384;
    u16* Bn = Bs + ((t + 1) & 1) * 16384;
    int kn = (t + 1) * 64;
    STAGE_B(0, Bn, kn);
    STAGE_B(1, Bn, kn);
    WAITVM(6); BARRIER();                 // {B(t), A0(t), A1(t)} landed
    half_mfma<MODE, 0>(Ac, Bc, wm, wn, quad, l16, bfr, acc);
    STAGE_A(0, An, kn);
    STAGE_A(1, An, kn);
    STAGE_A(2, An, kn);
    STAGE_A(3, An, kn);
    WAITVM(8); BARRIER();                 // {A2(t), A3(t)} landed
    half_mfma<MODE, 1>(Ac, Bc, wm, wn, quad, l16, bfr, acc);
  }
  {  // peeled last tile (parity 1), no staging: drain 2 / 0
    const u16* Ac = As + 16384;
    const u16* Bc = Bs + 16384;
    WAITVM(2); BARRIER();
    half_mfma<MODE, 0>(Ac, Bc, wm, wn, quad, l16, bfr, acc);
    WAITVM(0); BARRIER();
    half_mfma<MODE, 1>(Ac, Bc, wm, wn, quad, l16, bfr, acc);
  }
#undef STAGE_B
#undef STAGE_A

  // ---- epilogue: C/D layout col = lane&15, row = quad*4 + reg (m89/m91 verified) ----
  if (MODE == M_F32OUT) {
    float* C = (float*)Cv;
#pragma unroll
    for (int i = 0; i < 8; i++)
#pragma unroll
      for (int r = 0; r < 4; r++) {
        size_t row = (size_t)(m0 + wm * 128 + i * 16 + quad * 4 + r);
#pragma unroll
        for (int j = 0; j < 4; j++)
          C[row * N + (n0 + wn * 64 + j * 16 + l16)] = acc[i][j][r];
      }
  } else if (MODE == M_ROPE) {
    constexpr float QSCALE = 1.4426950408889634f * 0.08838834764831845f;
    const float scale = (n0 >> 11) ? 1.0f : QSCALE;   // q gets log2e/sqrt(128)
    u16* C = (u16*)Cv;
#pragma unroll
    for (int i = 0; i < 8; i++)
#pragma unroll
      for (int r = 0; r < 4; r++) {
        int row = m0 + wm * 128 + i * 16 + quad * 4 + r;
        int l = row & 2047;
#pragma unroll
        for (int j = 0; j < 4; j++) {
          int col = n0 + wn * 64 + j * 16 + l16;
          int dm = (col & 127) >> 1;
          float2 csv = cs[l * 64 + dm];
          float v = acc[i][j][r];
          float pv = __shfl_xor(v, 1);                 // partner lane (col^1)
          float sg = (l16 & 1) ? csv.y : -csv.y;       // even: -sin, odd: +sin
          C[(size_t)row * 4096 + col] = f2bf((v * csv.x + pv * sg) * scale);
        }
      }
  } else {
    // VT: swapped operands -> acc holds C^T; row = v-channel, col = token. vt[bh][d][l].
    u16* vt = (u16*)Cv;
#pragma unroll
    for (int j = 0; j < 4; j++)
#pragma unroll
      for (int r = 0; r < 4; r++) {
        int vch = n0 + wn * 64 + j * 16 + quad * 4 + r;   // 0..2047
        int h = vch >> 7, d = vch & 127;
#pragma unroll
        for (int i = 0; i < 8; i++) {
          int token = m0 + wm * 128 + i * 16 + l16;
          int b = token >> 11, lloc = token & 2047;
          vt[((size_t)(b * 16 + h)) * 262144 + (size_t)d * 2048 + lloc] =
              f2bf(acc[i][j][r]);
        }
      }
  }
}

// Merged QKV GEMM: bx<16 -> RoPE epilogue into qkv (stride 4096); bx>=16 -> V^T.
// XCD y-striping: each XCD owns a 4-row stripe of M-tiles (A rows L2-resident).
__global__ __launch_bounds__(512, 2) void gemm_qkv(const u16* __restrict__ xb,
                                                   const u16* __restrict__ wqkvb,
                                                   u16* __restrict__ qkvo,
                                                   u16* __restrict__ vto,
                                                   const float2* __restrict__ cs) {
  __shared__ u16 As[32768];
  __shared__ u16 Bs[32768];
  int id = blockIdx.x;
  int xcd = id & 7, sub = id >> 3;      // sub 0..95
  int bx = sub % 24, by = xcd * 4 + sub / 24;
  if (bx < 16)
    gemm256_core<M_ROPE>(xb, wqkvb, qkvo, cs, 0, by * 256, bx * 256, As, Bs);
  else
    gemm256_core<M_VT>(xb, wqkvb + (size_t)4096 * 2048, vto, nullptr, 0,
                       by * 256, (bx - 16) * 256, As, Bs);
}

__global__ __launch_bounds__(512, 2) void gemm_out_k(const u16* __restrict__ A,
                                                     const u16* __restrict__ Bt,
                                                     float* __restrict__ C) {
  __shared__ u16 As[32768];
  __shared__ u16 Bs[32768];
  int id = blockIdx.x;
  int xcd = id & 7, sub = id >> 3;      // sub 0..31
  int bx = sub % 8, by = xcd * 4 + sub / 8;
  gemm256_core<M_F32OUT>(A, Bt, C, nullptr, 2048, by * 256, bx * 256, As, Bs);
}

// ---------------- fused flash attention (fixed-base softmax, no online max) ----------------
// R9 (verified): 256 thr / 4 waves / 32 q-rows per wave (each K/V fragment read feeds
// TWO row-tiles), KVBLK=32, double-buffered K (2x8KB) + V (2x8KB) + padded P
// (128 x 40 = 10KB) = 43KB LDS -> 3 blocks/CU, 12 waves/CU. FENCE_LDS between the
// P-write loop and pf reads (R8 failure: compiler hoisted the cross-lane ds_read).
DEVFN int swz(int row, int chunk)   { return row * 128 + ((chunk ^ (row & 15)) << 3); } // 256B rows
DEVFN int swz32(int row, int chunk) { return row * 32  + (((chunk ^ (row & 3)) & 3) << 3); } // 64B rows

__global__ __launch_bounds__(256, 3) void attn_fused(const u16* __restrict__ qkv,
                                                     const u16* __restrict__ vt,
                                                     u16* __restrict__ out) {
  // S layout (u16 units): [0,4096)=Kb0 [4096,8192)=Kb1
  //                       [8192,12288)=Vb0 [12288,16384)=Vb1
  //                       [16384,21504)=P (128 rows x 40 elems, 80B stride: bank-spread)
  __shared__ u16 S[21504];                     // 43008 B
  u16* const Pb = S + 16384;
  int tid = threadIdx.x;
  int wv = tid >> 6, lane = tid & 63, quad = lane >> 4, l16 = lane & 15;
  int id = blockIdx.x;
  int xcd = id & 7, sub = id >> 3;             // sub 0..127
  int bh = ((sub >> 4) << 3) | xcd;            // 8 bh per XCD, all 16 qtiles local
  int qt = sub & 15;
  int b = bh >> 4, hh = bh & 15;
  const u16* qptr = qkv + (size_t)b * 2048 * 4096 + hh * 128;
  const u16* kptr = qptr + 2048;
  const u16* vptr = vt + (size_t)bh * 262144;
  int q0 = qt * 128;

  // ---- Q staging: 128 rows x 256B through S[0..16384), then pull to regs ----
#pragma unroll
  for (int j = 0; j < 8; j++) {
    int rb = wv * 4 + j * 16;
    int r = rb + (lane >> 4);
    int ck = (lane & 15) ^ (r & 15);
    gload16(&qptr[(size_t)(q0 + r) * 4096 + ck * 8], &S[rb * 128]);
  }
  __syncthreads();
  bf16x8 qf[2][4];
#pragma unroll
  for (int hf = 0; hf < 2; hf++)
#pragma unroll
    for (int ks = 0; ks < 4; ks++)
      qf[hf][ks] = *(const bf16x8*)&S[swz(wv * 32 + hf * 16 + l16, ks * 4 + quad)];
  __syncthreads();                             // qf reads done before kt=0 staging

  f32x4 o[2][8] = {};
  float l[2][4] = {{0.f, 0.f, 0.f, 0.f}, {0.f, 0.f, 0.f, 0.f}};

  // prologue: stage kt=0 into Kb0/Vb0 (K: 32 rows x 256B; V^T: 128 rows x 64B)
#pragma unroll
  for (int j = 0; j < 2; j++) {
    int rbk = wv * 4 + j * 16;
    int rk = rbk + (lane >> 4);
    int ckk = (lane & 15) ^ (rk & 15);
    gload16(&kptr[(size_t)rk * 4096 + ckk * 8], &S[rbk * 128]);
    int rbv = wv * 16 + j * 64;
    int rv = rbv + (lane >> 2);
    int ckv = (lane & 3) ^ (rv & 3);
    gload16(&vptr[(size_t)rv * 2048 + ckv * 8], &S[8192 + rbv * 32]);
  }

  for (int kt = 0; kt < 64; kt++) {
    int cur = kt & 1;
    const u16* Kc = S + cur * 4096;
    const u16* Vc = S + 8192 + cur * 4096;
    __syncthreads();   // auto vmcnt(0): drains cur-tile loads (1 iter old) + prior reads
    if (kt < 63) {     // prefetch kt+1 into the other buffer set
      int kk0 = (kt + 1) * 32;
      u16* kb = S + (cur ^ 1) * 4096;
      u16* vb = S + 8192 + (cur ^ 1) * 4096;
#pragma unroll
      for (int j = 0; j < 2; j++) {
        int rbk = wv * 4 + j * 16;
        int rk = rbk + (lane >> 4);
        int ckk = (lane & 15) ^ (rk & 15);
        gload16(&kptr[(size_t)(kk0 + rk) * 4096 + ckk * 8], &kb[rbk * 128]);
        int rbv = wv * 16 + j * 64;
        int rv = rbv + (lane >> 2);
        int ckv = (lane & 3) ^ (rv & 3);
        gload16(&vptr[(size_t)rv * 2048 + kk0 + ckv * 8], &vb[rbv * 32]);
      }
    }
    // S = Q K^T (scores in log2 domain via QSCALE folded into q).
    // One K-frag read feeds BOTH row-halves (the traffic halving).
    f32x4 s[2][2] = {};
#pragma unroll
    for (int ks = 0; ks < 4; ks++) {
#pragma unroll
      for (int nt = 0; nt < 2; nt++) {
        bf16x8 bfr = *(const bf16x8*)&Kc[swz(nt * 16 + l16, ks * 4 + quad)];
        s[0][nt] = __builtin_amdgcn_mfma_f32_16x16x32_bf16(qf[0][ks], bfr, s[0][nt], 0, 0, 0);
        s[1][nt] = __builtin_amdgcn_mfma_f32_16x16x32_bf16(qf[1][ks], bfr, s[1][nt], 0, 0, 0);
      }
    }
    // fixed-base softmax: p = exp2(s); lane-local row-sum; P -> padded private buffer
#pragma unroll
    for (int hf = 0; hf < 2; hf++)
#pragma unroll
      for (int nt = 0; nt < 2; nt++)
#pragma unroll
        for (int r = 0; r < 4; r++) {
          float p = exp2f(s[hf][nt][r]);
          l[hf][r] += p;
          int row = wv * 32 + hf * 16 + quad * 4 + r;
          int col = nt * 16 + l16;
          Pb[row * 40 + col] = f2bf(p);
        }
    // cross-lane P round-trip: force all P ds_writes to retire before pf ds_reads
    FENCE_LDS();
    // O += P V  (Vc holds V^T: rows = d, cols = 32 keys; K=32 -> one MFMA per tile).
    // One V-frag read feeds BOTH row-halves.
    {
      bf16x8 pf0 = *(const bf16x8*)&Pb[(wv * 32 + l16) * 40 + quad * 8];
      bf16x8 pf1 = *(const bf16x8*)&Pb[(wv * 32 + 16 + l16) * 40 + quad * 8];
#pragma unroll
      for (int nt = 0; nt < 8; nt++) {
        bf16x8 vf = *(const bf16x8*)&Vc[swz32(nt * 16 + l16, quad)];
        o[0][nt] = __builtin_amdgcn_mfma_f32_16x16x32_bf16(pf0, vf, o[0][nt], 0, 0, 0);
        o[1][nt] = __builtin_amdgcn_mfma_f32_16x16x32_bf16(pf1, vf, o[1][nt], 0, 0, 0);
      }
    }
  }
  // epilogue: reduce l across the 16 col-lanes once, divide, store bf16
#pragma unroll
  for (int hf = 0; hf < 2; hf++)
#pragma unroll
    for (int r = 0; r < 4; r++)
#pragma unroll
      for (int off = 1; off < 16; off <<= 1) l[hf][r] += __shfl_xor(l[hf][r], off, 16);
  u16* obase = out + ((size_t)b * 2048 + q0) * 2048 + hh * 128;
#pragma unroll
  for (int hf = 0; hf < 2; hf++)
#pragma unroll
    for (int r = 0; r < 4; r++) {
      float inv = 1.0f / l[hf][r];
      int row = wv * 32 + hf * 16 + quad * 4 + r;
#pragma unroll
      for (int nt = 0; nt < 8; nt++)
        obase[(size_t)row * 2048 + nt * 16 + l16] = f2bf(o[hf][nt][r] * inv);
    }
}

// ---------------- launch ----------------
extern "C" void kernel_launch(void* const* d_in, const int* in_sizes, int n_in,
                              void* d_out, int out_size, void* d_ws, size_t ws_size,
                              hipStream_t stream) {
  const float* x    = (const float*)d_in[0];   // [4,2048,2048]
  const float* cosp = (const float*)d_in[1];   // [2048,128]
  const float* sinp = (const float*)d_in[2];   // [2048,128]
  const float* wqkv = (const float*)d_in[3];   // [6144,2048]
  const float* wout = (const float*)d_in[4];   // [2048,2048]
  float* outp = (float*)d_out;                 // [4,2048,2048] fp32

  u16* ws    = (u16*)d_ws;
  u16* xb    = ws;                     // 16,777,216 elems (dead after gemm_qkv; reused)
  u16* wqkvb = xb + 16777216;          // 12,582,912 (row-permuted q/k)
  u16* woutb = wqkvb + 12582912;       //  4,194,304
  u16* qkv   = woutb + 4194304;        // 33,554,432 (q,k only; row stride 4096)
  u16* vt    = qkv + 33554432;         // 16,777,216
  float2* cs = (float2*)(vt + 16777216); // 131,072 float2 = 1 MB
  u16* attn  = xb;                     // alias: xb dead after gemm_qkv

  prep<<<32896, 256, 0, stream>>>(x, wqkv, wout, cosp, sinp, xb, wqkvb, woutb, cs);
  gemm_qkv<<<768, 512, 0, stream>>>(xb, wqkvb, qkv, vt, cs);
  attn_fused<<<1024, 256, 0, stream>>>(qkv, vt, attn);
  gemm_out_k<<<256, 512, 0, stream>>>(attn, woutb, outp);
}